// Round 5
// baseline (336.577 us; speedup 1.0000x reference)
//
#include <hip/hip_runtime.h>
#include <hip/hip_bf16.h>

// ConceptBottleneck fused kernel, MI355X (gfx950).
// B=8192, IN=768, C=64, H=64, E=16.  Inputs/outputs fp32; internal math bf16 MFMA.
// cb_fused_t: grid (B/128, C); block = 128-row batch tile x one concept.
//   R5 = R4 resubmit (R4 bench was an infra failure: container acquisition
//   died twice, no kernel verdict; design re-audited for hangs/OOB -- clean).
//   R4 design: A-DIRECT + 3 BLOCKS/CU.
//   - x (A-operand) is NEVER staged in LDS: each lane global_load_dwordx4's its
//     exact MFMA fragment (row-major [M][K], 16B contiguous per lane). Removes
//     x gll writes + A ds_reads from the shared 128B/clk LDS pipe (~45% of L1
//     LDS traffic) -> structural MfmaUtil ceiling rises.
//   - L1 W1 tiles: gll double-buffer wbuf[2][128*64], XOR-swizzled source /
//     swizzled reads (R2/R3-verified involution). Counted vmcnt: per iter issue
//     4 A-loads FIRST (in-order vmcnt retirement: A-use waits must not drain
//     the newer W glls), then 4 W-glls for kt+1, s_waitcnt vmcnt(8) (never 0
//     in loop), barrier, 32 MFMAs, barrier.
//   - Tail B-operands (W2p/W2n/W3p/W3n/cW1/cW2/cw3) read DIRECT from global
//     per wave (4x dup ~ 500 MB L2 reads, latency-hidden) -> no tail weight
//     staging, no weight-sync barrier.
//   - Tail stays wave-local barrier-free (R3-verified): hbP=wbuf[0],
//     hbN=wbuf[1] after the loop-end barrier; ONE final __syncthreads before
//     the cross-wave gate/output.
//   LDS 43520 B -> 3 blocks/CU (12 waves). launch_bounds(256,3) -> <=170 VGPR.
//   SPILL LAW (prev session): only accumulators may live across barriers.

#define B_   8192
#define IN_  768
#define C_   64
#define H_   64
#define E_   16
#define BM_  128

typedef __bf16 bf16x8 __attribute__((ext_vector_type(8)));
typedef float  f32x4  __attribute__((ext_vector_type(4)));

__device__ __forceinline__ f32x4 mfma16(bf16x8 a, bf16x8 b, f32x4 c) {
  return __builtin_amdgcn_mfma_f32_16x16x32_bf16(a, b, c, 0, 0, 0);
}

__device__ __forceinline__ bf16x8 cvt8(float4 a, float4 b) {
  bf16x8 r;
  r[0] = (__bf16)a.x; r[1] = (__bf16)a.y; r[2] = (__bf16)a.z; r[3] = (__bf16)a.w;
  r[4] = (__bf16)b.x; r[5] = (__bf16)b.y; r[6] = (__bf16)b.z; r[7] = (__bf16)b.w;
  return r;
}

__device__ __forceinline__ void zero_acc(f32x4 (&acc)[2][4]) {
  const f32x4 z = {0.f, 0.f, 0.f, 0.f};
#pragma unroll
  for (int mt = 0; mt < 2; ++mt)
#pragma unroll
    for (int nt = 0; nt < 4; ++nt) acc[mt][nt] = z;
}

// 16B global -> LDS direct (vmcnt-counted; LDS dest = wave-uniform base + lane*16)
__device__ __forceinline__ void gll16(const __bf16* g, __bf16* l) {
  __builtin_amdgcn_global_load_lds(
      (const __attribute__((address_space(1))) unsigned int*)g,
      (__attribute__((address_space(3))) unsigned int*)l, 16, 0, 0);
}

#define FENCE asm volatile("" ::: "memory")

// ============================ MAIN KERNEL ===================================
// LDS (43520 B -> 3 blocks/CU):
//  wbuf[2][128*64] : L1 W1 dbuf (rows 0-63 pos, 64-127 neg), XOR-swizzled.
//                    Tail alias: hbP = wbuf[0], hbN = wbuf[1] ([128][64] swz).
//  xcb[128][40]    : pos|neg embeddings (cols 0..15 pos, 16..31 neg)
//  conc[128]       : concept logits
struct __align__(16) SmemT {
  __bf16 wbuf[2 * 128 * 64];
  __bf16 xcb[BM_ * 40];
  float  conc[BM_];
};
static_assert(sizeof(SmemT) == 43520, "layout");
static_assert(sizeof(SmemT) <= 54613, "LDS: need 3 blocks/CU");

// Epilogue to stride-64 XOR-swizzled buffer: col=nt*16+l16, row=w*32+mt*16+quad*4+r.
// Slot for global chunk g at row = g^(row&7).
__device__ __forceinline__ void epi64s(__bf16* hb, f32x4 (&acc)[2][4],
                                       const float* __restrict__ bias,
                                       int wave, int quad, int l16) {
#pragma unroll
  for (int nt = 0; nt < 4; ++nt) {
    const int ch = nt * 2 + (l16 >> 3);
    const int cl = l16 & 7;
    const float bv = bias[nt * 16 + l16];
#pragma unroll
    for (int mt = 0; mt < 2; ++mt)
#pragma unroll
      for (int r = 0; r < 4; ++r) {
        const int row = wave * 32 + mt * 16 + quad * 4 + r;
        hb[row * 64 + (((ch ^ (row & 7)) << 3) | cl)] =
            (__bf16)fmaxf(acc[mt][nt][r] + bv, 0.f);
      }
  }
}

// [128,64] @ [64,64]: A = LDS swizzled hb; B = GLOBAL row-major [64 n][64 k].
__device__ __forceinline__ void gemm64g(const __bf16* A, const __bf16* __restrict__ Wg,
                                        f32x4 (&acc)[2][4], int wave, int quad, int l16) {
  const int s7 = l16 & 7;
  bf16x8 bb[2][4];
#pragma unroll
  for (int ks = 0; ks < 2; ++ks)
#pragma unroll
    for (int nt = 0; nt < 4; ++nt)
      bb[ks][nt] = *(const bf16x8*)(Wg + (nt * 16 + l16) * 64 + ks * 32 + quad * 8);
#pragma unroll
  for (int ks = 0; ks < 2; ++ks) {
    const int off = ((ks * 4 + quad) ^ s7) * 8;
    bf16x8 a[2];
#pragma unroll
    for (int mt = 0; mt < 2; ++mt)
      a[mt] = *(const bf16x8*)(A + (wave * 32 + mt * 16 + l16) * 64 + off);
#pragma unroll
    for (int mt = 0; mt < 2; ++mt)
#pragma unroll
      for (int nt = 0; nt < 4; ++nt)
        acc[mt][nt] = mfma16(a[mt], bb[ks][nt], acc[mt][nt]);
  }
}

// Layer-3: e = h2 @ W3t -> xcb[:, xc_off..+16). A = LDS swz; B = GLOBAL [16][64].
__device__ __forceinline__ void l3g(const __bf16* A, const __bf16* __restrict__ W3g,
                                    __bf16* xcb, const float* __restrict__ b3,
                                    int xc_off, int wave, int quad, int l16) {
  const int s7 = l16 & 7;
  f32x4 acc3[2];
  { const f32x4 z = {0.f, 0.f, 0.f, 0.f}; acc3[0] = z; acc3[1] = z; }
  bf16x8 bb[2];
#pragma unroll
  for (int ks = 0; ks < 2; ++ks)
    bb[ks] = *(const bf16x8*)(W3g + l16 * 64 + ks * 32 + quad * 8);
#pragma unroll
  for (int ks = 0; ks < 2; ++ks) {
    const int off = ((ks * 4 + quad) ^ s7) * 8;
#pragma unroll
    for (int mt = 0; mt < 2; ++mt) {
      bf16x8 a = *(const bf16x8*)(A + (wave * 32 + mt * 16 + l16) * 64 + off);
      acc3[mt] = mfma16(a, bb[ks], acc3[mt]);
    }
  }
  const float bv = b3[l16];
#pragma unroll
  for (int mt = 0; mt < 2; ++mt)
#pragma unroll
    for (int r = 0; r < 4; ++r) {
      const int row = wave * 32 + mt * 16 + quad * 4 + r;
      xcb[row * 40 + xc_off + l16] = (__bf16)(acc3[mt][r] + bv);
    }
}

// L1 MFMA step: A from registers (direct-global), B from swizzled wbuf half.
__device__ __forceinline__ void l1_step(const __bf16* wb, const bf16x8 (&av)[2][2],
                                        f32x4 (&accP)[2][4], f32x4 (&accN)[2][4],
                                        int quad, int l16) {
  const int sx = l16 & 7;
#pragma unroll
  for (int ks = 0; ks < 2; ++ks) {
    const int pc = ((ks * 4 + quad) ^ sx) * 8;
    bf16x8 bp[4], bn[4];
#pragma unroll
    for (int nt = 0; nt < 4; ++nt) {
      bp[nt] = *(const bf16x8*)(wb + (nt * 16 + l16) * 64 + pc);
      bn[nt] = *(const bf16x8*)(wb + (64 + nt * 16 + l16) * 64 + pc);
    }
#pragma unroll
    for (int mt = 0; mt < 2; ++mt)
#pragma unroll
      for (int nt = 0; nt < 4; ++nt) {
        accP[mt][nt] = mfma16(av[mt][ks], bp[nt], accP[mt][nt]);
        accN[mt][nt] = mfma16(av[mt][ks], bn[nt], accN[mt][nt]);
      }
  }
}

__global__ __launch_bounds__(256, 3) void cb_fused_t(
    const __bf16* __restrict__ x,
    const __bf16* __restrict__ pW1t, const float* __restrict__ pb1,
    const __bf16* __restrict__ pW2t, const float* __restrict__ pb2,
    const __bf16* __restrict__ pW3t, const float* __restrict__ pb3,
    const __bf16* __restrict__ nW1t, const float* __restrict__ nb1,
    const __bf16* __restrict__ nW2t, const float* __restrict__ nb2,
    const __bf16* __restrict__ nW3t, const float* __restrict__ nb3,
    const __bf16* __restrict__ cW1t, const float* __restrict__ cb1,
    const __bf16* __restrict__ cW2t, const float* __restrict__ cb2,
    const __bf16* __restrict__ cw3,  const float* __restrict__ cb3,
    float* __restrict__ out_emb, float* __restrict__ out_con)
{
  __shared__ SmemT sm;
  const int tid  = threadIdx.x;
  const int wave = tid >> 6, lane = tid & 63;
  const int quad = lane >> 4, l16 = lane & 15;
  const int row0 = blockIdx.x * BM_;
  const int c    = blockIdx.y;

  // per-concept pointers
  const __bf16* pg   = pW1t + (size_t)c * 64 * IN_;
  const __bf16* ng   = nW1t + (size_t)c * 64 * IN_;
  const float*  pb1c = pb1 + c * 64;
  const float*  nb1c = nb1 + c * 64;
  const float*  pb2c = pb2 + c * 64;
  const float*  nb2c = nb2 + c * 64;

  // ---------- layer 1 COMBINED: A direct-global, W1 gll dbuf ----------
  f32x4 accP[2][4]; zero_acc(accP);
  f32x4 accN[2][4]; zero_acc(accN);

  const __bf16* xg = x + (size_t)row0 * IN_;
  // W gll source (swizzled): wave 0,1 -> pos rows, wave 2,3 -> neg rows.
  const int lrow = lane >> 3, lchunk = (lane & 7) ^ lrow;
  const __bf16* wsrc = (wave < 2)
      ? pg + (size_t)(wave * 32 + lrow) * IN_ + lchunk * 8
      : ng + (size_t)((wave - 2) * 32 + lrow) * IN_ + lchunk * 8;
  __bf16* const d0 = sm.wbuf + wave * 32 * 64;
  __bf16* const d1 = sm.wbuf + 8192 + wave * 32 * 64;

  // prologue: W tile 0 -> wbuf[0]
#pragma unroll
  for (int j = 0; j < 4; ++j)
    gll16(wsrc + j * 8 * IN_, d0 + j * 8 * 64);

  // per-lane A base: row = wave*32 + l16 (+16 for mt=1), k-chunk = quad*8
  const __bf16* ag = xg + (size_t)(wave * 32 + l16) * IN_ + quad * 8;

  for (int kt = 0; kt < 12; ++kt) {
    // A(kt) fragments: issue FIRST (before glls) so compiler A-use waits
    // (in-order vmcnt retirement) don't drain the newer W(kt+1) glls.
    bf16x8 av[2][2];
    av[0][0] = *(const bf16x8*)(ag + kt * 64);
    av[0][1] = *(const bf16x8*)(ag + kt * 64 + 32);
    av[1][0] = *(const bf16x8*)(ag + (size_t)16 * IN_ + kt * 64);
    av[1][1] = *(const bf16x8*)(ag + (size_t)16 * IN_ + kt * 64 + 32);
    __builtin_amdgcn_sched_barrier(0);     // pin A-issue before gll-issue
    if (kt < 11) {
      const __bf16* wk = wsrc + (kt + 1) * 64;
      __bf16* nd = ((kt + 1) & 1) ? d1 : d0;
#pragma unroll
      for (int j = 0; j < 4; ++j)
        gll16(wk + j * 8 * IN_, nd + j * 8 * 64);
      // outstanding: W(kt)[4 oldest] + A(kt)[4] + W(kt+1)[4] -> wait W(kt) landed
      asm volatile("s_waitcnt vmcnt(8)" ::: "memory");
    } else {
      // outstanding: W(11)[4 oldest] + A(11)[4]
      asm volatile("s_waitcnt vmcnt(4)" ::: "memory");
    }
    __builtin_amdgcn_s_barrier();
    __builtin_amdgcn_sched_barrier(0);
    FENCE;
    l1_step(sm.wbuf + (kt & 1) * 8192, av, accP, accN, quad, l16);
    FENCE;
    __builtin_amdgcn_s_barrier();   // all reads done before next overwrite
    __builtin_amdgcn_sched_barrier(0);
    FENCE;
  }

  // ---------- tail: wave-local, barrier-free; B operands direct from L2 ------
  __bf16* hbP = sm.wbuf;           // [128][64] swz (wbuf[0] dead after kt=10+barrier)
  __bf16* hbN = sm.wbuf + 8192;    // wbuf[1] dead after kt=11+barrier

  epi64s(hbP, accP, pb1c, wave, quad, l16);
  epi64s(hbN, accN, nb1c, wave, quad, l16);

  // L2 pos+neg
  f32x4 acc2P[2][4]; zero_acc(acc2P);
  f32x4 acc2N[2][4]; zero_acc(acc2N);
  gemm64g(hbP, pW2t + (size_t)c * 4096, acc2P, wave, quad, l16);
  gemm64g(hbN, nW2t + (size_t)c * 4096, acc2N, wave, quad, l16);
  epi64s(hbP, acc2P, pb2c, wave, quad, l16);
  epi64s(hbN, acc2N, nb2c, wave, quad, l16);

  // L3 pos+neg -> xcb
  l3g(hbP, pW3t + (size_t)c * 1024, sm.xcb, pb3 + c * 16, 0,  wave, quad, l16);
  l3g(hbN, nW3t + (size_t)c * 1024, sm.xcb, nb3 + c * 16, 16, wave, quad, l16);

  // cp layer 1: [128,32] @ [32,64]; A = xcb (stride 40), B = cW1t [64][32] global
  f32x4 acc1[2][4]; zero_acc(acc1);
  {
    const __bf16* c1 = cW1t + (size_t)c * 2048;
    bf16x8 a[2], bb[4];
#pragma unroll
    for (int nt = 0; nt < 4; ++nt)
      bb[nt] = *(const bf16x8*)(c1 + (nt * 16 + l16) * 32 + quad * 8);
#pragma unroll
    for (int mt = 0; mt < 2; ++mt)
      a[mt] = *(const bf16x8*)&sm.xcb[(wave * 32 + mt * 16 + l16) * 40 + quad * 8];
#pragma unroll
    for (int mt = 0; mt < 2; ++mt)
#pragma unroll
      for (int nt = 0; nt < 4; ++nt)
        acc1[mt][nt] = mfma16(a[mt], bb[nt], acc1[mt][nt]);
  }
  epi64s(hbP, acc1, cb1 + c * 64, wave, quad, l16);

  // cp layer 2
  f32x4 accC[2][4]; zero_acc(accC);
  gemm64g(hbP, cW2t + (size_t)c * 4096, accC, wave, quad, l16);
  epi64s(hbP, accC, cb2 + c * 64, wave, quad, l16);

  // cp layer 3 (N=1 via MFMA; B nonzero only in lane col 0)
  {
    f32x4 acc3[2];
    { const f32x4 z = {0.f, 0.f, 0.f, 0.f}; acc3[0] = z; acc3[1] = z; }
    const int s7 = l16 & 7;
#pragma unroll
    for (int ks = 0; ks < 2; ++ks) {
      const int off = ((ks * 4 + quad) ^ s7) * 8;
      bf16x8 bbv = {};
      if (l16 == 0) bbv = *(const bf16x8*)(cw3 + (size_t)c * 64 + ks * 32 + quad * 8);
#pragma unroll
      for (int mt = 0; mt < 2; ++mt) {
        bf16x8 a = *(const bf16x8*)(hbP + (wave * 32 + mt * 16 + l16) * 64 + off);
        acc3[mt] = mfma16(a, bbv, acc3[mt]);
      }
    }
    if (l16 == 0) {
      float bv = cb3[c];
#pragma unroll
      for (int mt = 0; mt < 2; ++mt)
#pragma unroll
        for (int r = 0; r < 4; ++r)
          sm.conc[wave * 32 + mt * 16 + quad * 4 + r] = acc3[mt][r] + bv;
    }
  }
  __syncthreads();   // conc + xcb now needed cross-wave

  // ---- gate + outputs (fp32) ----
  for (int ii = tid; ii < BM_ * E_; ii += 256) {
    int row = ii >> 4, e = ii & 15;
    float cv = sm.conc[row];
    float w  = fminf(fmaxf(cv * 0.5f + 0.5f, 0.f), 1.f);
    float pv2 = (float)sm.xcb[row * 40 + e];
    float nv2 = (float)sm.xcb[row * 40 + 16 + e];
    out_emb[(size_t)(row0 + row) * (E_ * C_) + e * C_ + c] = pv2 * w + nv2 * (1.f - w);
  }
  if (tid < 128) out_con[(size_t)(row0 + tid) * C_ + c] = sm.conc[tid];
}

// ------------- prep_all: ONE flat 1D launch, no dead blocks -------------------
#define TSEG 5
#define PSEG 5
struct PrepArgs {
  const float* tsrc[TSEG];
  __bf16*      tdst[TSEG];
  int tstart[TSEG + 1];
  int ktiles[TSEG];            // K/64
  const float* psrc[PSEG];
  __bf16*      pdst[PSEG];
  int pstart[PSEG + 1];        // block starts (after tblocks)
  int pchunks[PSEG];           // total 8-elem chunks in segment
  int kdiv8[PSEG];
  int N[PSEG];                 // 1 = plain copy, else transpose inner stride
  int tblocks;
};

__global__ __launch_bounds__(256) void prep_all(PrepArgs a) {
  const int tid = threadIdx.x;
  const int b = blockIdx.x;
  __shared__ __bf16 lt[64 * 72];
  if (b < a.tblocks) {
    int s = 0;
    while (s < TSEG - 1 && b >= a.tstart[s + 1]) ++s;
    const int idx = b - a.tstart[s];
    const int kt = idx % a.ktiles[s];
    const int c  = idx / a.ktiles[s];
    const int K  = a.ktiles[s] * 64;
    const float* src = a.tsrc[s] + (size_t)c * K * 64 + (size_t)kt * 64 * 64;
    __bf16*      dst = a.tdst[s] + (size_t)c * 64 * K + kt * 64;
    const int r = tid >> 4, c4 = (tid & 15) * 4;
#pragma unroll
    for (int it = 0; it < 4; ++it) {
      int k = r + it * 16;
      float4 v = *(const float4*)(src + (size_t)k * 64 + c4);
      lt[(c4 + 0) * 72 + k] = (__bf16)v.x;
      lt[(c4 + 1) * 72 + k] = (__bf16)v.y;
      lt[(c4 + 2) * 72 + k] = (__bf16)v.z;
      lt[(c4 + 3) * 72 + k] = (__bf16)v.w;
    }
    __syncthreads();
    const int n = tid >> 3, i = tid & 7;
#pragma unroll
    for (int it = 0; it < 2; ++it) {
      int nn = n + it * 32;
      *(uint4*)(dst + (size_t)nn * K + i * 8) = *(const uint4*)&lt[nn * 72 + i * 8];
    }
  } else {
    const int bb = b - a.tblocks;
    int s = 0;
    while (s < PSEG - 1 && bb >= a.pstart[s + 1]) ++s;
    const int lb  = bb - a.pstart[s];
    const int nch = a.pchunks[s];
    const int kc  = a.kdiv8[s];
    const int N   = a.N[s];
#pragma unroll
    for (int j = 0; j < 4; ++j) {
      const int li = (lb * 4 + j) * 256 + tid;
      if (li >= nch) break;
      if (N == 1) {
        const float4* src = (const float4*)a.psrc[s] + (size_t)li * 2;
        float4 v0 = src[0], v1 = src[1];
        *(uint4*)(a.pdst[s] + (size_t)li * 8) = __builtin_bit_cast(uint4, cvt8(v0, v1));
      } else {
        int rn = li / kc;
        int k0 = (li - rn * kc) * 8;
        int cc = rn / N;
        int n  = rn - cc * N;
        const float* src = a.psrc[s] + ((size_t)cc * kc * 8 + k0) * N + n;
        bf16x8 r;
#pragma unroll
        for (int jj = 0; jj < 8; ++jj) r[jj] = (__bf16)src[(size_t)jj * N];
        *(uint4*)(a.pdst[s] + (size_t)rn * kc * 8 + k0) = __builtin_bit_cast(uint4, r);
      }
    }
  }
}

// ============================== launch =======================================
extern "C" void kernel_launch(void* const* d_in, const int* in_sizes, int n_in,
                              void* d_out, int out_size, void* d_ws, size_t ws_size,
                              hipStream_t stream) {
  const float* xf   = (const float*)d_in[0];
  const float* pW1f = (const float*)d_in[1];
  const float* pb1f = (const float*)d_in[2];
  const float* pW2f = (const float*)d_in[3];
  const float* pb2f = (const float*)d_in[4];
  const float* pW3f = (const float*)d_in[5];
  const float* pb3f = (const float*)d_in[6];
  const float* nW1f = (const float*)d_in[7];
  const float* nb1f = (const float*)d_in[8];
  const float* nW2f = (const float*)d_in[9];
  const float* nb2f = (const float*)d_in[10];
  const float* nW3f = (const float*)d_in[11];
  const float* nb3f = (const float*)d_in[12];
  const float* cW1f = (const float*)d_in[13];
  const float* cb1f = (const float*)d_in[14];
  const float* cW2f = (const float*)d_in[15];
  const float* cb2f = (const float*)d_in[16];
  const float* cW3f = (const float*)d_in[17];
  const float* cb3f = (const float*)d_in[18];

  float* out_emb = (float*)d_out;
  float* out_con = out_emb + (size_t)B_ * E_ * C_;

  const int cx   = B_ * IN_;          // 6291456
  const int cW1c = C_ * IN_ * H_;     // 3145728
  const int cW2c = C_ * H_ * H_;      // 262144
  const int cW3c = C_ * H_ * E_;      // 65536
  const int ccW1 = C_ * 2 * E_ * H_;  // 131072
  const int ccW3 = C_ * H_;           // 4096

  __bf16* w = (__bf16*)d_ws;
  size_t o = 0;
  __bf16* xw   = w + o; o += cx;
  __bf16* pw1t = w + o; o += cW1c;
  __bf16* nw1t = w + o; o += cW1c;
  __bf16* pw2t = w + o; o += cW2c;
  __bf16* nw2t = w + o; o += cW2c;
  __bf16* cw2t = w + o; o += cW2c;
  __bf16* pw3t = w + o; o += cW3c;
  __bf16* nw3t = w + o; o += cW3c;
  __bf16* cw1t = w + o; o += ccW1;
  __bf16* cw3w = w + o; o += ccW3;

  PrepArgs a;
  int tb = 0, pb = 0;
  {
    const float* tsrc[TSEG] = {pW1f, nW1f, pW2f, nW2f, cW2f};
    __bf16*      tdst[TSEG] = {pw1t, nw1t, pw2t, nw2t, cw2t};
    const int    tk[TSEG]   = {12,   12,   1,    1,    1};
    for (int i = 0; i < TSEG; ++i) {
      a.tsrc[i] = tsrc[i]; a.tdst[i] = tdst[i]; a.ktiles[i] = tk[i];
      a.tstart[i] = tb;
      tb += tk[i] * C_;
    }
    a.tstart[TSEG] = tb;
    a.tblocks = tb;

    const float* psrc[PSEG] = {xf, cW3f, pW3f, nW3f, cW1f};
    __bf16*      pdst[PSEG] = {xw, cw3w, pw3t, nw3t, cw1t};
    const int    pKs[PSEG]  = {0,  0,    64,   64,   32};
    const int    pNs[PSEG]  = {1,  1,    16,   16,   64};
    const int    pels[PSEG] = {cx, ccW3, cW3c, cW3c, ccW1};
    for (int i = 0; i < PSEG; ++i) {
      a.psrc[i] = psrc[i]; a.pdst[i] = pdst[i];
      a.pchunks[i] = pels[i] / 8;
      a.kdiv8[i] = (pNs[i] == 1) ? (pels[i] / 8) : (pKs[i] / 8);
      a.N[i] = pNs[i];
      a.pstart[i] = pb;
      pb += (pels[i] / 8 + 1023) / 1024;   // 256 threads x 4 chunks per block
    }
    a.pstart[PSEG] = pb;
  }
  prep_all<<<tb + pb, 256, 0, stream>>>(a);

  dim3 grid(B_ / BM_, C_);
  cb_fused_t<<<grid, 256, 0, stream>>>(xw,
      pw1t, pb1f, pw2t, pb2f, pw3t, pb3f,
      nw1t, nb1f, nw2t, nb2f, nw3t, nb3f,
      cw1t, cb1f, cw2t, cb2f, cw3w, cb3f,
      out_emb, out_con);
}